// Round 2
// baseline (655.789 us; speedup 1.0000x reference)
//
#include <hip/hip_runtime.h>

#define N_NODES 100000
#define N_EDGES 3200000
#define D 256
#define OVF_MAX 8192

#define RPB 128                     // rows per bucket
#define NBUCK 782                   // ceil(N_NODES / RPB)
#define CAPB 5120                   // bucket capacity (mean 4096, +16 sigma)
#define SCAP 4608                   // LDS-staged records per bucket (+8 sigma)

#define CHUNK 4096                  // edges per bin block
#define NBLK_A ((N_EDGES + CHUNK - 1) / CHUNK)     // 782
#define NGRP 196                    // scan groups: ceil(782/4)

#define CAST_BLOCKS 6250            // 25.6M elems / (256 thr * 16)
#define GEMM_BLOCKS (N_NODES / 16)  // 6250

typedef __attribute__((ext_vector_type(8))) short bf16x8;
typedef __attribute__((ext_vector_type(4))) float f32x4;

// ---------------- static device scratch (rebuilt every call) ----------------
// W^T packed MFMA-fragment-contiguous: [ntile16][kstep8][lane64][8 bf16]
__device__ unsigned short g_wtp[(size_t)16 * 8 * 64 * 8];   // 128 KB
__device__ unsigned short g_xb[(size_t)N_NODES * D];        // 51.2 MB x in bf16
__device__ unsigned       g_y[(size_t)N_NODES * (D / 2)];   // 51.2 MB Y=A*x bf16
__device__ int   g_bucket_cur[NBUCK];
__device__ int2  g_binned[(size_t)NBUCK * CAPB];            // 32 MB
__device__ int   g_novf;
__device__ int   g_ovf_row[OVF_MAX];
__device__ int2  g_ovf_edge[OVF_MAX];

// fp32 -> bf16 round-to-nearest-even
__device__ __forceinline__ unsigned short f2bf(float f) {
    unsigned u = __float_as_uint(f);
    unsigned r = u + 0x7fffu + ((u >> 16) & 1u);
    return (unsigned short)(r >> 16);
}

// ---------------------------------- setup: pack W^T bf16 + zero cursors
// packed index p = ((nt*8 + s)*64 + lane)*8 + i :
//   n = nt*16 + (lane&15), k = s*32 + (lane>>4)*8 + i  -> source W[k][n]
__global__ void setup_kernel(const float* __restrict__ W) {
    const int tid = threadIdx.x;
    if (blockIdx.x < 64) {
        int pb = (blockIdx.x * 256 + tid) * 4;
        #pragma unroll
        for (int j = 0; j < 4; ++j) {
            int p    = pb + j;
            int i8   = p & 7;
            int lane = (p >> 3) & 63;
            int s    = (p >> 9) & 7;
            int nt   = p >> 12;
            int n = nt * 16 + (lane & 15);
            int k = s * 32 + (lane >> 4) * 8 + i8;
            g_wtp[p] = f2bf(W[(size_t)k * D + n]);
        }
    }
    for (int i = blockIdx.x * blockDim.x + tid; i < NBUCK;
         i += gridDim.x * blockDim.x)
        g_bucket_cur[i] = 0;
    if (blockIdx.x == 0 && tid == 0) g_novf = 0;
}

// ------------- fused: bin edges (no dep on x) || cast x fp32 -> bf16
__launch_bounds__(256)
__global__ void bin_cast_kernel(const float* __restrict__ x,
                                const float* __restrict__ edge_val,
                                const int* __restrict__ edge_row,
                                const int* __restrict__ edge_col) {
    __shared__ int2 rec[CHUNK];              // 32 KB
    __shared__ unsigned short bid[CHUNK];    // 8 KB  (bucket of each record)
    __shared__ int cnt[NGRP * 4];            // 784 (padded)
    __shared__ int pre[NBUCK + 1];
    __shared__ int bas[NBUCK];
    __shared__ int gs[NGRP];
    __shared__ int gofs[NGRP];
    const int tid = threadIdx.x;
    const int b = blockIdx.x;

    if (b < NBLK_A) {
        // ---------------- bin by row>>7, bucket-sorted LDS staging + bursts
        const int e0 = b * CHUNK;
        for (int q = tid; q < NGRP * 4; q += 256) cnt[q] = 0;
        __syncthreads();
        #pragma unroll
        for (int j = 0; j < CHUNK / 256; ++j) {
            int e = e0 + tid + j * 256;
            if (e < N_EDGES) atomicAdd(&cnt[edge_row[e] >> 7], 1);
        }
        __syncthreads();
        // two-level parallel exclusive scan over 782 buckets
        if (tid < NGRP) {
            const int* c = &cnt[tid * 4];
            gs[tid] = c[0] + c[1] + c[2] + c[3];
        }
        __syncthreads();
        if (tid < NGRP) {
            int s = 0;
            for (int j = 0; j < tid; ++j) s += gs[j];
            gofs[tid] = s;
        }
        __syncthreads();
        for (int q = tid; q < NBUCK; q += 256) {
            int p = gofs[q >> 2];
            for (int j = q & ~3; j < q; ++j) p += cnt[j];
            pre[q] = p;
        }
        if (tid == 0) pre[NBUCK] = gofs[NGRP - 1] + gs[NGRP - 1];
        __syncthreads();
        // reserve global bucket space (one atomic per non-empty bucket)
        for (int q = tid; q < NBUCK; q += 256)
            bas[q] = cnt[q] ? atomicAdd(&g_bucket_cur[q], cnt[q]) : 0;
        __syncthreads();
        for (int q = tid; q < NGRP * 4; q += 256) cnt[q] = 0;  // reuse: offsets
        __syncthreads();
        // place records bucket-sorted in LDS, remember bucket id
        #pragma unroll
        for (int j = 0; j < CHUNK / 256; ++j) {
            int e = e0 + tid + j * 256;
            if (e < N_EDGES) {
                int r = edge_row[e];
                int q = r >> 7;
                int o = atomicAdd(&cnt[q], 1);
                int pos = pre[q] + o;
                int2 pk;
                pk.x = edge_col[e] | ((r & 127) << 17);  // col:17b | row_local:7b
                pk.y = __float_as_int(edge_val[e]);
                rec[pos] = pk;
                bid[pos] = (unsigned short)q;
            }
        }
        __syncthreads();
        // flush: consecutive i -> consecutive dest within bucket (bursts)
        const int total = pre[NBUCK];
        for (int i = tid; i < total; i += 256) {
            int q = bid[i];
            int dest = bas[q] + (i - pre[q]);
            int2 pk = rec[i];
            if (dest < CAPB) {
                g_binned[(size_t)q * CAPB + dest] = pk;
            } else {
                int o = atomicAdd(&g_novf, 1);
                if (o < OVF_MAX) {
                    g_ovf_row[o] = (q << 7) | (pk.x >> 17);
                    int2 ov; ov.x = pk.x & 0x1FFFF; ov.y = pk.y;
                    g_ovf_edge[o] = ov;
                }
            }
        }
    } else {
        // ---------------- cast: 16 floats per thread, exact-fit grid
        const size_t base = (size_t)(b - NBLK_A) * 4096 + (size_t)tid * 16;
        const float4* xp = (const float4*)&x[base];
        float4 f0 = xp[0], f1 = xp[1], f2 = xp[2], f3 = xp[3];
        unsigned short o[16];
        o[ 0]=f2bf(f0.x); o[ 1]=f2bf(f0.y); o[ 2]=f2bf(f0.z); o[ 3]=f2bf(f0.w);
        o[ 4]=f2bf(f1.x); o[ 5]=f2bf(f1.y); o[ 6]=f2bf(f1.z); o[ 7]=f2bf(f1.w);
        o[ 8]=f2bf(f2.x); o[ 9]=f2bf(f2.y); o[10]=f2bf(f2.z); o[11]=f2bf(f2.w);
        o[12]=f2bf(f3.x); o[13]=f2bf(f3.y); o[14]=f2bf(f3.z); o[15]=f2bf(f3.w);
        uint4* dst = (uint4*)&g_xb[base];
        dst[0] = *(const uint4*)&o[0];
        dst[1] = *(const uint4*)&o[8];
    }
}

// ---------------------------------------------------------------- SpMM
// Y = A * x_bf16. One 512-thread block per 128-row bucket: counting-sort the
// bucket's records by row_local in LDS, then 4 groups x 128 threads gather;
// group g owns rows g*32..g*32+31; thread t owns features 2t, 2t+1.
__launch_bounds__(512)
__global__ void spmm_kernel() {
    __shared__ int2 srec[SCAP];          // 36.9 KB
    __shared__ int rcnt[RPB];
    __shared__ int rofs[RPB];
    __shared__ int rcur[RPB];
    const int k   = blockIdx.x;
    const int tid = threadIdx.x;
    const int nrec_all = min(g_bucket_cur[k], CAPB);
    const int nstage   = min(nrec_all, SCAP);
    const int2* src = &g_binned[(size_t)k * CAPB];

    if (tid < RPB) { rcnt[tid] = 0; rcur[tid] = 0; }
    __syncthreads();
    for (int i = tid; i < nstage; i += 512)
        atomicAdd(&rcnt[src[i].x >> 17], 1);
    __syncthreads();
    if (tid < RPB) {                     // brute-force exclusive scan (128 keys)
        int s = 0;
        for (int j = 0; j < tid; ++j) s += rcnt[j];
        rofs[tid] = s;
    }
    __syncthreads();
    for (int i = tid; i < nstage; i += 512) {
        int2 pk = src[i];
        int rl  = pk.x >> 17;
        int pos = rofs[rl] + atomicAdd(&rcur[rl], 1);
        srec[pos] = pk;
    }
    __syncthreads();

    const int grp = tid >> 7;            // 4 groups
    const int t   = tid & 127;
    const unsigned* xb = (const unsigned*)g_xb;
    const int novf = min(g_novf, OVF_MAX);

    for (int rr = 0; rr < 32; ++rr) {
        const int rl  = grp * 32 + rr;
        const int row = k * RPB + rl;
        if (row >= N_NODES) break;
        const int cnt = rcnt[rl];
        const int ofs = rofs[rl];
        float a0 = 0.f, a1 = 0.f;
        int i = 0;
        for (; i + 3 < cnt; i += 4) {
            int2 e0 = srec[ofs + i];
            int2 e1 = srec[ofs + i + 1];
            int2 e2 = srec[ofs + i + 2];
            int2 e3 = srec[ofs + i + 3];
            unsigned p0 = xb[(size_t)(e0.x & 0x1FFFF) * (D / 2) + t];
            unsigned p1 = xb[(size_t)(e1.x & 0x1FFFF) * (D / 2) + t];
            unsigned p2 = xb[(size_t)(e2.x & 0x1FFFF) * (D / 2) + t];
            unsigned p3 = xb[(size_t)(e3.x & 0x1FFFF) * (D / 2) + t];
            float v0 = __int_as_float(e0.y);
            float v1 = __int_as_float(e1.y);
            float v2 = __int_as_float(e2.y);
            float v3 = __int_as_float(e3.y);
            a0 += v0 * __uint_as_float(p0 << 16);
            a1 += v0 * __uint_as_float(p0 & 0xffff0000u);
            a0 += v1 * __uint_as_float(p1 << 16);
            a1 += v1 * __uint_as_float(p1 & 0xffff0000u);
            a0 += v2 * __uint_as_float(p2 << 16);
            a1 += v2 * __uint_as_float(p2 & 0xffff0000u);
            a0 += v3 * __uint_as_float(p3 << 16);
            a1 += v3 * __uint_as_float(p3 & 0xffff0000u);
        }
        for (; i < cnt; ++i) {
            int2 e0 = srec[ofs + i];
            unsigned p0 = xb[(size_t)(e0.x & 0x1FFFF) * (D / 2) + t];
            float v0 = __int_as_float(e0.y);
            a0 += v0 * __uint_as_float(p0 << 16);
            a1 += v0 * __uint_as_float(p0 & 0xffff0000u);
        }
        // tail: records that didn't fit the LDS stage (prob ~1e-12)
        for (int j = nstage; j < nrec_all; ++j) {
            int2 pk = src[j];
            if ((pk.x >> 17) == rl) {
                unsigned p0 = xb[(size_t)(pk.x & 0x1FFFF) * (D / 2) + t];
                float v0 = __int_as_float(pk.y);
                a0 += v0 * __uint_as_float(p0 << 16);
                a1 += v0 * __uint_as_float(p0 & 0xffff0000u);
            }
        }
        // bucket-overflow fallback (empty in practice)
        if (novf > 0) {
            for (int j = 0; j < novf; ++j) {
                if (g_ovf_row[j] == row) {
                    int2 ee = g_ovf_edge[j];
                    float v0 = __int_as_float(ee.y);
                    unsigned p0 = xb[(size_t)ee.x * (D / 2) + t];
                    a0 += v0 * __uint_as_float(p0 << 16);
                    a1 += v0 * __uint_as_float(p0 & 0xffff0000u);
                }
            }
        }
        // NO relu here: out = relu(Y @ W) is applied after the GEMM
        g_y[(size_t)row * (D / 2) + t] =
            (unsigned)f2bf(a0) | ((unsigned)f2bf(a1) << 16);
    }
}

// --------------------------- out = relu(Y @ W), per-wave 16x64 tile, K=256
__launch_bounds__(256)
__global__ void gemm_kernel(float* __restrict__ out) {
    __shared__ float tile[4][16][68];
    const int g    = blockIdx.x;
    const int wave = threadIdx.x >> 6;
    const int lane = threadIdx.x & 63;
    const int m0   = g * 16;
    const int n0   = wave * 64;
    const int lm   = lane & 15;
    const int q    = lane >> 4;

    const unsigned short* Yb = (const unsigned short*)g_y;
    f32x4 acc0 = {}, acc1 = {}, acc2 = {}, acc3 = {};

    #pragma unroll
    for (int s = 0; s < 8; ++s) {
        bf16x8 av = *(const bf16x8*)&Yb[(size_t)(m0 + lm) * D + s * 32 + q * 8];
        const unsigned short* bp =
            &g_wtp[((size_t)(wave * 4) * 8 + s) * 512 + lane * 8];
        bf16x8 b0 = *(const bf16x8*)&bp[0 * 4096];
        bf16x8 b1 = *(const bf16x8*)&bp[1 * 4096];
        bf16x8 b2 = *(const bf16x8*)&bp[2 * 4096];
        bf16x8 b3 = *(const bf16x8*)&bp[3 * 4096];
        acc0 = __builtin_amdgcn_mfma_f32_16x16x32_bf16(av, b0, acc0, 0, 0, 0);
        acc1 = __builtin_amdgcn_mfma_f32_16x16x32_bf16(av, b1, acc1, 0, 0, 0);
        acc2 = __builtin_amdgcn_mfma_f32_16x16x32_bf16(av, b2, acc2, 0, 0, 0);
        acc3 = __builtin_amdgcn_mfma_f32_16x16x32_bf16(av, b3, acc3, 0, 0, 0);
    }

    #pragma unroll
    for (int r = 0; r < 4; ++r) {
        tile[wave][q * 4 + r][ 0 + lm] = acc0[r];
        tile[wave][q * 4 + r][16 + lm] = acc1[r];
        tile[wave][q * 4 + r][32 + lm] = acc2[r];
        tile[wave][q * 4 + r][48 + lm] = acc3[r];
    }
    const int row  = lane >> 2;
    const int cseg = (lane & 3) * 16;
    float ov[16];
    #pragma unroll
    for (int j = 0; j < 16; ++j)
        ov[j] = fmaxf(tile[wave][row][cseg + j], 0.f);
    float* dst = &out[(size_t)(m0 + row) * D + n0 + cseg];
    #pragma unroll
    for (int j = 0; j < 4; ++j)
        __builtin_nontemporal_store(*(const f32x4*)&ov[j * 4], (f32x4*)&dst[j * 4]);
}

// ---------------------------------------------------------------- launcher
extern "C" void kernel_launch(void* const* d_in, const int* in_sizes, int n_in,
                              void* d_out, int out_size, void* d_ws, size_t ws_size,
                              hipStream_t stream) {
    const float* x        = (const float*)d_in[0];
    const float* weight   = (const float*)d_in[1];
    const float* edge_val = (const float*)d_in[2];
    const int*   edge_row = (const int*)d_in[3];
    const int*   edge_col = (const int*)d_in[4];
    float* out = (float*)d_out;

    setup_kernel<<<64, 256, 0, stream>>>(weight);
    bin_cast_kernel<<<NBLK_A + CAST_BLOCKS, 256, 0, stream>>>(x, edge_val, edge_row, edge_col);
    spmm_kernel<<<NBUCK, 512, 0, stream>>>();
    gemm_kernel<<<GEMM_BLOCKS, 256, 0, stream>>>(out);
}